// Round 11
// baseline (54.190 us; speedup 1.0000x reference)
//
#include <hip/hip_runtime.h>

// Depthwise cross-correlation, B*C = 32768 planes: x[32][32] (*) k[8][8] -> out[25][25].
// softmax(weight) sums to 1.0 -> output == correlation; weight unused.
//
// Round-9 structure (best, 47us): thread = (plane, ox) computes one output
// column (25 outputs); x in LDS as packed-bf16 pairs, TWO parity copies per
// row (A: pairs (2i,2i+1), B: pairs (2i+1,2i+2)); v_dot2_f32_bf16 inner loop;
// row stride 36, per-plane bank shifts {0,12,8}.
// Round-11 change: OCCUPANCY. r10 falsified the remat theory (VGPR 52 = taps
// resident + early acc stores); the 47us is LDS(27us) + mem(22us) serialized
// at 16 waves/CU. Block 512 / PPB 16 -> LDS 78KB/block, 2 blocks/CU,
// 32 waves/CU: stage(mem) and compute(LDS) phases of different waves overlap.

#define NPLANES (128 * 256)
#define PPB 16
#define RST 36                      // row stride (dwords)
#define XP  1184                    // plane stride (dwords): %32==0
#define KTB (PPB * XP)              // taps base (18944, %4==0)
#define KTS 36                      // taps plane stride
#define LDS_DW (KTB + PPB * KTS)    // 19520 dw = 78080 B -> 2 blocks/CU
#define OH 25
#define OW 25

__device__ __forceinline__ unsigned cvt_pk_bf16(float a, float b) {
    unsigned r;  // lo = bf16(a), hi = bf16(b)
    asm("v_cvt_pk_bf16_f32 %0, %1, %2" : "=v"(r) : "v"(a), "v"(b));
    return r;
}
__device__ __forceinline__ void dot2(float& acc, unsigned x2, unsigned k2) {
    asm("v_dot2_f32_bf16 %0, %1, %2, %0" : "+v"(acc) : "v"(x2), "v"(k2));
}

__device__ __forceinline__ int plane_shift(int pl) {
    const int m = pl % 3;
    return (m == 0) ? 0 : (m == 1) ? 12 : 8;
}

__global__ __launch_bounds__(512)
void dwxcorr_kernel(const float* __restrict__ x,
                    const float* __restrict__ kern,
                    float* __restrict__ out) {
    __shared__ unsigned ldsu[LDS_DW];
    const int tid = threadIdx.x;
    const int plane0 = blockIdx.x * PPB;   // NPLANES % PPB == 0 -> no tail

    // ---- Stage x: unit = (plane, row, half-row of 16 floats) -> A[8],B[8] packed dwords ----
#pragma unroll
    for (int it = 0; it < 2; ++it) {
        const int u    = tid + it * 512;   // PPB*64 = 1024 units
        const int pl   = u >> 6;
        const int rh   = u & 63;
        const int row  = rh >> 1;
        const int half = rh & 1;
        const float* g = x + (size_t)(plane0 + pl) * 1024 + row * 32 + half * 16;
        float f[17];
        const float4 v0 = *reinterpret_cast<const float4*>(g + 0);
        const float4 v1 = *reinterpret_cast<const float4*>(g + 4);
        const float4 v2 = *reinterpret_cast<const float4*>(g + 8);
        const float4 v3 = *reinterpret_cast<const float4*>(g + 12);
        f[0]=v0.x; f[1]=v0.y; f[2]=v0.z; f[3]=v0.w;
        f[4]=v1.x; f[5]=v1.y; f[6]=v1.z; f[7]=v1.w;
        f[8]=v2.x; f[9]=v2.y; f[10]=v2.z; f[11]=v2.w;
        f[12]=v3.x; f[13]=v3.y; f[14]=v3.z; f[15]=v3.w;
        // half0 needs x[row][16] for B[7]=(f15,f16); half1's last B pair is never read.
        f[16] = (half == 0) ? g[16] : f[15];
        unsigned A[8], Bp[8];
#pragma unroll
        for (int t = 0; t < 8; ++t) A[t]  = cvt_pk_bf16(f[2*t],     f[2*t + 1]);
#pragma unroll
        for (int t = 0; t < 8; ++t) Bp[t] = cvt_pk_bf16(f[2*t + 1], f[2*t + 2]);
        unsigned* base = &ldsu[pl * XP + plane_shift(pl) + row * RST + half * 8];
        *reinterpret_cast<uint4*>(base + 0)  = make_uint4(A[0], A[1], A[2], A[3]);
        *reinterpret_cast<uint4*>(base + 4)  = make_uint4(A[4], A[5], A[6], A[7]);
        *reinterpret_cast<uint4*>(base + 16) = make_uint4(Bp[0], Bp[1], Bp[2], Bp[3]);
        *reinterpret_cast<uint4*>(base + 20) = make_uint4(Bp[4], Bp[5], Bp[6], Bp[7]);
    }
    // ---- Stage taps: packed even pairs, flat (ky*8+kx)/2 order ----
    if (tid < PPB * 16) {
        const int pl = tid >> 4;
        const int o4 = tid & 15;
        const float4 v =
            *reinterpret_cast<const float4*>(kern + (size_t)(plane0 + pl) * 64 + o4 * 4);
        unsigned* kb = &ldsu[KTB + pl * KTS + o4 * 2];
        kb[0] = cvt_pk_bf16(v.x, v.y);
        kb[1] = cvt_pk_bf16(v.z, v.w);
    }
    __syncthreads();

    const int pb = tid / 25;
    if (pb >= PPB) return;           // tids 400..511 idle after staging
    const int ox = tid % 25;

    // ---- Taps -> 32 packed dwords (register-resident; r10 proved they stay) ----
    unsigned kt[32];
    {
        const unsigned* kp = &ldsu[KTB + pb * KTS];
#pragma unroll
        for (int i = 0; i < 8; ++i) {
            const uint4 q = *reinterpret_cast<const uint4*>(kp + 4 * i);
            kt[4*i+0] = q.x; kt[4*i+1] = q.y; kt[4*i+2] = q.z; kt[4*i+3] = q.w;
        }
    }

    float acc[OH];
#pragma unroll
    for (int i = 0; i < OH; ++i) acc[i] = 0.f;

    // Window: copy (ox&1), starting pair (ox>>1); 4 dwords/row serve all 8 ky.
    const unsigned* xb =
        &ldsu[pb * XP + plane_shift(pb) + (ox & 1) * 16 + (ox >> 1)];
#pragma unroll
    for (int r = 0; r < 32; ++r) {
        const unsigned xw0 = xb[r * RST + 0];
        const unsigned xw1 = xb[r * RST + 1];
        const unsigned xw2 = xb[r * RST + 2];
        const unsigned xw3 = xb[r * RST + 3];
#pragma unroll
        for (int ky = 0; ky < 8; ++ky) {
            const int oy = r - ky;               // compile-time with full unroll
            if (oy >= 0 && oy < OH) {
                dot2(acc[oy], xw0, kt[ky * 4 + 0]);
                dot2(acc[oy], xw1, kt[ky * 4 + 1]);
                dot2(acc[oy], xw2, kt[ky * 4 + 2]);
                dot2(acc[oy], xw3, kt[ky * 4 + 3]);
            }
        }
    }

    // ---- Coalesced stores: consecutive ox lanes -> consecutive addresses ----
    float* op = out + (size_t)(plane0 + pb) * (OH * OW) + ox;
#pragma unroll
    for (int oy = 0; oy < OH; ++oy) op[oy * OW] = acc[oy];
}

extern "C" void kernel_launch(void* const* d_in, const int* in_sizes, int n_in,
                              void* d_out, int out_size, void* d_ws, size_t ws_size,
                              hipStream_t stream) {
    const float* x = (const float*)d_in[0];
    const float* k = (const float*)d_in[1];
    // d_in[2] (weight) unused: softmax weights sum to exactly 1.
    float* out = (float*)d_out;
    const int nblocks = NPLANES / PPB;   // 2048
    dwxcorr_kernel<<<nblocks, 512, 0, stream>>>(x, k, out);
}

// Round 13
// 43.840 us; speedup vs baseline: 1.2361x; 1.2361x over previous
//
#include <hip/hip_runtime.h>

// Depthwise cross-correlation, B*C = 32768 planes: x[32][32] (*) k[8][8] -> out[25][25].
// softmax(weight) sums to 1.0 -> output == correlation; weight unused.
//
// Thread = (plane, ox): one output column, 25 outputs (r9's winning mapping).
// Single packed-bf16 copy of x; odd output columns form windows in-register
// with v_alignbit_b32 (shift=(ox&1)*16). LDS/plane 2368 B -> PPB=8, block=256,
// 20.1 KB/block -> 8 blocks/CU = 32 waves/CU (2x r9/r10's 16).
// Round-13 fix: XP 584 -> 592. r12's plane-7 (shift 12) x-write overran its
// 584-dword region into the taps base, corrupting plane 0's taps (absmax 19.7).
// 592 >= 576+12 holds any shift; %32==16 adds even/odd plane bank alternation.

#define NPLANES (128 * 256)
#define PPB 8
#define RST 18                      // row stride (dwords): 16 data + 2 pad
#define XP  592                     // plane stride: >= 576+max_shift, %4==0, %32==16
#define KTB (PPB * XP)              // taps base (4736, %4==0)
#define KTS 36                      // taps plane stride
#define LDS_DW (KTB + PPB * KTS)    // 5024 dw = 20096 B -> 8 blocks/CU
#define OH 25
#define OW 25

__device__ __forceinline__ unsigned cvt_pk_bf16(float a, float b) {
    unsigned r;  // lo = bf16(a), hi = bf16(b)
    asm("v_cvt_pk_bf16_f32 %0, %1, %2" : "=v"(r) : "v"(a), "v"(b));
    return r;
}
__device__ __forceinline__ void dot2(float& acc, unsigned x2, unsigned k2) {
    asm("v_dot2_f32_bf16 %0, %1, %2, %0" : "+v"(acc) : "v"(x2), "v"(k2));
}
__device__ __forceinline__ unsigned alignb(unsigned hi, unsigned lo, unsigned sh) {
    unsigned r;  // ((hi:lo) >> sh)[31:0]; sh=0 -> lo
    asm("v_alignbit_b32 %0, %1, %2, %3" : "=v"(r) : "v"(hi), "v"(lo), "v"(sh));
    return r;
}

__device__ __forceinline__ int plane_shift(int pl) {
    const int m = pl % 3;           // bank de-correlation, even dwords (b64 align)
    return (m == 0) ? 0 : (m == 1) ? 12 : 8;
}

__global__ __launch_bounds__(256)
void dwxcorr_kernel(const float* __restrict__ x,
                    const float* __restrict__ kern,
                    float* __restrict__ out) {
    __shared__ unsigned ldsu[LDS_DW];
    const int tid = threadIdx.x;
    const int plane0 = blockIdx.x * PPB;   // NPLANES % PPB == 0 -> no tail

    // ---- Stage x: unit = (plane, row, half-row of 16 floats) -> 8 packed dwords ----
#pragma unroll
    for (int it = 0; it < 2; ++it) {
        const int u    = tid + it * 256;   // PPB*64 = 512 units
        const int pl   = u >> 6;
        const int rh   = u & 63;
        const int row  = rh >> 1;
        const int half = rh & 1;
        const float* g = x + (size_t)(plane0 + pl) * 1024 + row * 32 + half * 16;
        const float4 v0 = *reinterpret_cast<const float4*>(g + 0);
        const float4 v1 = *reinterpret_cast<const float4*>(g + 4);
        const float4 v2 = *reinterpret_cast<const float4*>(g + 8);
        const float4 v3 = *reinterpret_cast<const float4*>(g + 12);
        unsigned A[8];
        A[0] = cvt_pk_bf16(v0.x, v0.y); A[1] = cvt_pk_bf16(v0.z, v0.w);
        A[2] = cvt_pk_bf16(v1.x, v1.y); A[3] = cvt_pk_bf16(v1.z, v1.w);
        A[4] = cvt_pk_bf16(v2.x, v2.y); A[5] = cvt_pk_bf16(v2.z, v2.w);
        A[6] = cvt_pk_bf16(v3.x, v3.y); A[7] = cvt_pk_bf16(v3.z, v3.w);
        unsigned* base = &ldsu[pl * XP + plane_shift(pl) + row * RST + half * 8];
        *reinterpret_cast<uint2*>(base + 0) = make_uint2(A[0], A[1]);
        *reinterpret_cast<uint2*>(base + 2) = make_uint2(A[2], A[3]);
        *reinterpret_cast<uint2*>(base + 4) = make_uint2(A[4], A[5]);
        *reinterpret_cast<uint2*>(base + 6) = make_uint2(A[6], A[7]);
    }
    // ---- Stage taps: packed even pairs, flat (ky*8+kx)/2 order ----
    if (tid < PPB * 16) {
        const int pl = tid >> 4;
        const int o4 = tid & 15;
        const float4 v =
            *reinterpret_cast<const float4*>(kern + (size_t)(plane0 + pl) * 64 + o4 * 4);
        unsigned* kb = &ldsu[KTB + pl * KTS + o4 * 2];
        kb[0] = cvt_pk_bf16(v.x, v.y);
        kb[1] = cvt_pk_bf16(v.z, v.w);
    }
    __syncthreads();

    const int pb = tid / 25;
    if (pb >= PPB) return;           // tids 200..255 idle after staging
    const int ox = tid % 25;

    // ---- Taps -> 32 packed dwords (register-resident, r10-verified) ----
    unsigned kt[32];
    {
        const unsigned* kp = &ldsu[KTB + pb * KTS];
#pragma unroll
        for (int i = 0; i < 8; ++i) {
            const uint4 q = *reinterpret_cast<const uint4*>(kp + 4 * i);
            kt[4*i+0] = q.x; kt[4*i+1] = q.y; kt[4*i+2] = q.z; kt[4*i+3] = q.w;
        }
    }

    float acc[OH];
#pragma unroll
    for (int i = 0; i < OH; ++i) acc[i] = 0.f;

    // Window: 5 dwords (pairs p0..p0+4), shifted by (ox&1)*16 bits in-register.
    const unsigned sh = (ox & 1) * 16;
    const unsigned* xb = &ldsu[pb * XP + plane_shift(pb) + (ox >> 1)];
#pragma unroll
    for (int r = 0; r < 32; ++r) {
        const unsigned* rp = xb + r * RST;
        const unsigned d0 = rp[0], d1 = rp[1], d2 = rp[2], d3 = rp[3], d4 = rp[4];
        const unsigned w0 = alignb(d1, d0, sh);
        const unsigned w1 = alignb(d2, d1, sh);
        const unsigned w2 = alignb(d3, d2, sh);
        const unsigned w3 = alignb(d4, d3, sh);
#pragma unroll
        for (int ky = 0; ky < 8; ++ky) {
            const int oy = r - ky;               // compile-time with full unroll
            if (oy >= 0 && oy < OH) {
                dot2(acc[oy], w0, kt[ky * 4 + 0]);
                dot2(acc[oy], w1, kt[ky * 4 + 1]);
                dot2(acc[oy], w2, kt[ky * 4 + 2]);
                dot2(acc[oy], w3, kt[ky * 4 + 3]);
            }
        }
    }

    // ---- Coalesced stores: consecutive ox lanes -> consecutive addresses ----
    float* op = out + (size_t)(plane0 + pb) * (OH * OW) + ox;
#pragma unroll
    for (int oy = 0; oy < OH; ++oy) op[oy * OW] = acc[oy];
}

extern "C" void kernel_launch(void* const* d_in, const int* in_sizes, int n_in,
                              void* d_out, int out_size, void* d_ws, size_t ws_size,
                              hipStream_t stream) {
    const float* x = (const float*)d_in[0];
    const float* k = (const float*)d_in[1];
    // d_in[2] (weight) unused: softmax weights sum to exactly 1.
    float* out = (float*)d_out;
    const int nblocks = NPLANES / PPB;   // 4096
    dwxcorr_kernel<<<nblocks, 256, 0, stream>>>(x, k, out);
}